// Round 2
// baseline (1065.968 us; speedup 1.0000x reference)
//
#include <hip/hip_runtime.h>
#include <stdint.h>

// ---------------------------------------------------------------------------
// TransformerBlock: bf16 MFMA implementation. OUTPUT IS FP32 (reference dtype).
// x:(4,16,256,1024) fp32. d_out: 16.7M fp32.
// Pipeline:
//   transpose-cast weights (fp32 -> bf16, B^T layout)      [5 launches]
//   mod = silu(time_emb) @ mod_w + mod_b                   [1]
//   h = rmsnorm(x)* (1+scale1)+shift1 -> bf16              [1]
//   qkv = h @ qkv_w^T                 (GEMM mode 0)        [1]
//   attn: per (b,t,h) fused MFMA softmax                   [1]
//   x1 = x + gate1 * (attn @ out_w)   (GEMM mode 1 -> d_out fp32)
//   h2 = rmsnorm(x1)*(1+scale2)+shift2 -> bf16
//   h1 = silu(h2 @ w1)                (GEMM mode 2)
//   hid = h1 * (h2 @ w2)              (GEMM mode 3, in place)
//   out = x1 + gate2 * (hid @ w3)     (GEMM mode 4, fp32 RMW on d_out)
// ---------------------------------------------------------------------------

using bf16x8 = __attribute__((ext_vector_type(8))) short;
using f32x4  = __attribute__((ext_vector_type(4))) float;

__device__ __forceinline__ float bf2f(uint16_t h) {
  union { uint32_t u; float f; } v; v.u = ((uint32_t)h) << 16; return v.f;
}
__device__ __forceinline__ uint16_t f2bf(float f) {
  union { float f; uint32_t u; } v; v.f = f;
  uint32_t r = v.u + 0x7FFFu + ((v.u >> 16) & 1u);
  return (uint16_t)(r >> 16);
}
__device__ __forceinline__ float silu(float x) { return x / (1.0f + __expf(-x)); }

// ---------------------------------------------------------------------------
// Transpose-cast: wt[n][k] = (bf16) w[k][n].  w is (K,N) fp32 row-major.
// ---------------------------------------------------------------------------
__global__ __launch_bounds__(256)
void transpose_cast(const float* __restrict__ w, uint16_t* __restrict__ wt,
                    int K, int N) {
  __shared__ float tile[32][33];
  int n0 = blockIdx.x * 32, k0 = blockIdx.y * 32;
  int tx = threadIdx.x & 31, ty = threadIdx.x >> 5;  // ty in [0,8)
#pragma unroll
  for (int it = 0; it < 4; ++it) {
    int r = ty + it * 8;
    tile[r][tx] = w[(k0 + r) * N + n0 + tx];
  }
  __syncthreads();
#pragma unroll
  for (int it = 0; it < 4; ++it) {
    int r = ty + it * 8;
    wt[(n0 + r) * K + k0 + tx] = f2bf(tile[tx][r]);
  }
}

// ---------------------------------------------------------------------------
// mod = silu(time_emb) @ mod_w + mod_b      (4 x 6144, K=1024)
// grid 24, block 1024 (4 k-slices x 256 cols)
// ---------------------------------------------------------------------------
__global__ __launch_bounds__(1024)
void mod_kernel(const float* __restrict__ te, const float* __restrict__ mw,
                const float* __restrict__ mb, float* __restrict__ mod) {
  __shared__ float ste[4096];          // silu(te) [b][k]
  __shared__ float red[4][4][256];     // [slice][b][col]
  int tid = threadIdx.x;
  for (int i = tid; i < 4096; i += 1024) { float v = te[i]; ste[i] = silu(v); }
  __syncthreads();
  int kslice = tid >> 8, cl = tid & 255;
  int col = blockIdx.x * 256 + cl;
  float acc[4] = {0.f, 0.f, 0.f, 0.f};
  for (int kk = 0; kk < 256; ++kk) {
    int k = kslice * 256 + kk;
    float wv = mw[k * 6144 + col];
#pragma unroll
    for (int b = 0; b < 4; ++b) acc[b] += ste[b * 1024 + k] * wv;
  }
#pragma unroll
  for (int b = 0; b < 4; ++b) red[kslice][b][cl] = acc[b];
  __syncthreads();
  if (kslice == 0) {
#pragma unroll
    for (int b = 0; b < 4; ++b)
      mod[b * 6144 + col] =
          red[0][b][cl] + red[1][b][cl] + red[2][b][cl] + red[3][b][cl] + mb[col];
  }
}

// ---------------------------------------------------------------------------
// RMSNorm + modulation -> bf16.  One block per row (1024 cols, 256 thr x4).
// x is fp32 (either the input tensor or the fp32 residual in d_out).
// ---------------------------------------------------------------------------
__global__ __launch_bounds__(256)
void norm_kernel(const float* __restrict__ xf,
                 const float* __restrict__ w, const float* __restrict__ mod,
                 int shift_off, int scale_off, uint16_t* __restrict__ out) {
  int row = blockIdx.x;
  int b = row >> 12;                 // 4096 rows per batch
  int tid = threadIdx.x;
  float4 t = *(const float4*)(xf + (size_t)row * 1024 + tid * 4);
  float v[4] = {t.x, t.y, t.z, t.w};
  float ss = v[0] * v[0] + v[1] * v[1] + v[2] * v[2] + v[3] * v[3];
#pragma unroll
  for (int off = 1; off < 64; off <<= 1) ss += __shfl_xor(ss, off);
  __shared__ float red[4];
  if ((tid & 63) == 0) red[tid >> 6] = ss;
  __syncthreads();
  float tot = red[0] + red[1] + red[2] + red[3];
  float rinv = rsqrtf(tot * (1.0f / 1024.0f) + 1e-6f);
  const float* mrow = mod + b * 6144;
  uint16_t o[4];
#pragma unroll
  for (int c = 0; c < 4; ++c) {
    int col = tid * 4 + c;
    float hv = v[c] * rinv * w[col] * (1.0f + mrow[scale_off + col]) + mrow[shift_off + col];
    o[c] = f2bf(hv);
  }
  uint2 pk;
  pk.x = (uint32_t)o[0] | ((uint32_t)o[1] << 16);
  pk.y = (uint32_t)o[2] | ((uint32_t)o[3] << 16);
  *(uint2*)(out + (size_t)row * 1024 + tid * 4) = pk;
}

// ---------------------------------------------------------------------------
// GEMM: C(M,N) = A(M,K)bf16 @ Bt(N,K)bf16, 128x128x32 tile, 4 waves (2x2),
// each wave 64x64 via 4x4 tiles of v_mfma_f32_16x16x32_bf16.
// MODE: 0 store bf16 | 1 x+gate1*C -> d_out fp32 | 2 silu bf16 | 3 h1*C bf16
//       4 xio += gate2*C (fp32 RMW on d_out)
// ---------------------------------------------------------------------------
template <int MODE>
__global__ __launch_bounds__(256)
void gemm_bt(const uint16_t* __restrict__ A, const uint16_t* __restrict__ Bt,
             int M, int N, int K,
             uint16_t* __restrict__ obf,
             const float* __restrict__ xin, const float* __restrict__ mod,
             const uint16_t* __restrict__ h1, float* __restrict__ xio) {
  constexpr int LDT = 40;                 // 32 + 8 pad (bank-conflict-free frag reads)
  __shared__ uint16_t As[128 * LDT];
  __shared__ uint16_t Bs[128 * LDT];
  const int tiles_n = (N + 127) >> 7;
  const int tm = blockIdx.x / tiles_n, tn = blockIdx.x % tiles_n;
  const int m0 = tm * 128, n0 = tn * 128;
  const int tid = threadIdx.x;
  const int wave = tid >> 6, lane = tid & 63;
  const int wm = (wave & 1) * 64, wn = (wave >> 1) * 64;
  const int col = lane & 15, quad = lane >> 4;

  const int ar = tid >> 1, ac = (tid & 1) * 16;
  const uint16_t* Ag = A + (size_t)(m0 + ar) * K + ac;
  int brow = n0 + ar; if (brow >= N) brow = N - 1;
  const uint16_t* Bg = Bt + (size_t)brow * K + ac;

  f32x4 acc[4][4];
#pragma unroll
  for (int i = 0; i < 4; ++i)
#pragma unroll
    for (int j = 0; j < 4; ++j) acc[i][j] = (f32x4){0.f, 0.f, 0.f, 0.f};

  for (int k0 = 0; k0 < K; k0 += 32) {
    uint4 a0 = *(const uint4*)(Ag + k0);
    uint4 a1 = *(const uint4*)(Ag + k0 + 8);
    uint4 b0 = *(const uint4*)(Bg + k0);
    uint4 b1 = *(const uint4*)(Bg + k0 + 8);
    __syncthreads();
    *(uint4*)(As + ar * LDT + ac) = a0;
    *(uint4*)(As + ar * LDT + ac + 8) = a1;
    *(uint4*)(Bs + ar * LDT + ac) = b0;
    *(uint4*)(Bs + ar * LDT + ac + 8) = b1;
    __syncthreads();
    bf16x8 af[4], bf[4];
#pragma unroll
    for (int i = 0; i < 4; ++i)
      af[i] = *(const bf16x8*)(As + (wm + i * 16 + col) * LDT + quad * 8);
#pragma unroll
    for (int j = 0; j < 4; ++j)
      bf[j] = *(const bf16x8*)(Bs + (wn + j * 16 + col) * LDT + quad * 8);
#pragma unroll
    for (int i = 0; i < 4; ++i)
#pragma unroll
      for (int j = 0; j < 4; ++j)
        acc[i][j] = __builtin_amdgcn_mfma_f32_16x16x32_bf16(af[i], bf[j], acc[i][j], 0, 0, 0);
  }

  // epilogue
#pragma unroll
  for (int i = 0; i < 4; ++i) {
#pragma unroll
    for (int j = 0; j < 4; ++j) {
#pragma unroll
      for (int r = 0; r < 4; ++r) {
        int row = m0 + wm + i * 16 + quad * 4 + r;
        int cn = n0 + wn + j * 16 + col;
        if (cn >= N) continue;
        float c = acc[i][j][r];
        if (MODE == 0) {
          obf[(size_t)row * N + cn] = f2bf(c);
        } else if (MODE == 1) {
          int b = row >> 12;
          size_t idx = (size_t)row * 1024 + cn;
          float g = mod[b * 6144 + 2048 + cn];
          xio[idx] = xin[idx] + g * c;
        } else if (MODE == 2) {
          obf[(size_t)row * N + cn] = f2bf(silu(c));
        } else if (MODE == 3) {
          size_t idx = (size_t)row * N + cn;
          obf[idx] = f2bf(bf2f(h1[idx]) * c);
        } else {  // MODE 4
          int b = row >> 12;
          size_t idx = (size_t)row * 1024 + cn;
          float g = mod[b * 6144 + 5120 + cn];
          xio[idx] = xio[idx] + g * c;
        }
      }
    }
  }
}

// ---------------------------------------------------------------------------
// Fused attention: one block per (slice, qchunk); slice=(b*16+t)*16+h, S=256.
// LDS: Ks (256x64 bf16, chunk-XOR-swizzled) + Vt (64x256 bf16, swizzled) = 64KB.
// Per wave: one 16-row q-tile -> 16x256 scores (C layout) -> softmax in-reg
// (shfl over 16-lane col groups) -> P through LDS (A layout) -> PV -> store.
// ---------------------------------------------------------------------------
__global__ __launch_bounds__(256)
void attn_kernel(const uint16_t* __restrict__ qkv, uint16_t* __restrict__ out) {
  __shared__ uint16_t lds[32768];  // 64 KB: Ks [0,16384), Vt [16384,32768)
  const int tid = threadIdx.x;
  const int bid = blockIdx.x;
  const int slice = bid >> 2, qc = bid & 3;
  const int bt = slice >> 4, h = slice & 15;
  const int row0 = bt * 256;
  const int wave = tid >> 6, lane = tid & 63;
  const int col = lane & 15, quad = lane >> 4;

  // ---- stage K (swizzled: chunk kc stored at kc ^ (kr&7)) ----
  {
    int kr = tid;
    const uint16_t* kp = qkv + (size_t)(row0 + kr) * 3072 + 1024 + h * 64;
    uint16_t* ks = lds + kr * 64;
#pragma unroll
    for (int kc = 0; kc < 8; ++kc) {
      uint4 v = *(const uint4*)(kp + kc * 8);
      *(uint4*)(ks + ((kc ^ (kr & 7)) << 3)) = v;
    }
  }
  // ---- stage V^T (Vt[d][kr], kr-pair-chunk krc stored at krc ^ (d&7)) ----
  {
    int p = tid & 127, dh = tid >> 7;
    const uint16_t* vp0 = qkv + (size_t)(row0 + 2 * p) * 3072 + 2048 + h * 64 + dh * 32;
    const uint16_t* vp1 = vp0 + 3072;
    uint16_t r0[32], r1[32];
#pragma unroll
    for (int i = 0; i < 4; ++i) {
      *(uint4*)(r0 + i * 8) = *(const uint4*)(vp0 + i * 8);
      *(uint4*)(r1 + i * 8) = *(const uint4*)(vp1 + i * 8);
    }
    uint32_t* vt = (uint32_t*)(lds + 16384);
    int krc = p >> 2;
#pragma unroll
    for (int i = 0; i < 32; ++i) {
      int d = dh * 32 + i;
      uint32_t val = (uint32_t)r0[i] | ((uint32_t)r1[i] << 16);
      vt[d * 128 + ((krc ^ (d & 7)) << 2) + (p & 3)] = val;
    }
  }
  __syncthreads();

  // ---- Q fragments (direct from global) ----
  const int qrow = qc * 64 + wave * 16 + col;
  const uint16_t* qp = qkv + (size_t)(row0 + qrow) * 3072 + h * 64;
  bf16x8 aq0 = *(const bf16x8*)(qp + quad * 8);
  bf16x8 aq1 = *(const bf16x8*)(qp + 32 + quad * 8);

  // ---- scores: S[q][k] = q . k, 16 k-tiles ----
  f32x4 sc[16];
#pragma unroll
  for (int t = 0; t < 16; ++t) {
    int n = t * 16 + col;
    const uint16_t* kb = lds + n * 64;
    bf16x8 b0 = *(const bf16x8*)(kb + ((quad ^ (n & 7)) << 3));
    bf16x8 b1 = *(const bf16x8*)(kb + (((4 + quad) ^ (n & 7)) << 3));
    f32x4 s = (f32x4){0.f, 0.f, 0.f, 0.f};
    s = __builtin_amdgcn_mfma_f32_16x16x32_bf16(aq0, b0, s, 0, 0, 0);
    s = __builtin_amdgcn_mfma_f32_16x16x32_bf16(aq1, b1, s, 0, 0, 0);
    sc[t] = s;
  }

  // ---- softmax over k (rows r = quad*4+i, cols = 16 lanes x 16 tiles) ----
  const float scale = 0.125f;  // HD^-0.5
  float inv[4];
#pragma unroll
  for (int i = 0; i < 4; ++i) {
    float m = -1e30f;
#pragma unroll
    for (int t = 0; t < 16; ++t) m = fmaxf(m, sc[t][i]);
    m = fmaxf(m, __shfl_xor(m, 1));
    m = fmaxf(m, __shfl_xor(m, 2));
    m = fmaxf(m, __shfl_xor(m, 4));
    m = fmaxf(m, __shfl_xor(m, 8));
    m *= scale;
    float sum = 0.f;
#pragma unroll
    for (int t = 0; t < 16; ++t) {
      float p = __expf(sc[t][i] * scale - m);
      sc[t][i] = p;
      sum += p;
    }
    sum += __shfl_xor(sum, 1);
    sum += __shfl_xor(sum, 2);
    sum += __shfl_xor(sum, 4);
    sum += __shfl_xor(sum, 8);
    inv[i] = 1.0f / sum;
  }
  __syncthreads();  // all waves done reading Ks before P overlays it

  // ---- write P (bf16, A-layout source) into per-wave slice of Ks region ----
  uint16_t* P = lds + wave * 4096;
#pragma unroll
  for (int t = 0; t < 16; ++t) {
    int pcb = t * 2 + (col >> 3);
#pragma unroll
    for (int i = 0; i < 4; ++i) {
      int r = quad * 4 + i;
      P[r * 256 + ((pcb ^ (r & 7)) << 3) + (col & 7)] = f2bf(sc[t][i] * inv[i]);
    }
  }

  // ---- PV: out[q][d] = sum_k P[q][k] V[k][d] ----
  f32x4 o[4];
#pragma unroll
  for (int nt = 0; nt < 4; ++nt) o[nt] = (f32x4){0.f, 0.f, 0.f, 0.f};
  const uint16_t* Vt = lds + 16384;
#pragma unroll
  for (int c = 0; c < 8; ++c) {
    int pc = c * 4 + quad;
    bf16x8 ap = *(const bf16x8*)(P + col * 256 + ((pc ^ (col & 7)) << 3));
#pragma unroll
    for (int nt = 0; nt < 4; ++nt) {
      int d = nt * 16 + col;
      bf16x8 bv = *(const bf16x8*)(Vt + d * 256 + ((pc ^ (d & 7)) << 3));
      o[nt] = __builtin_amdgcn_mfma_f32_16x16x32_bf16(ap, bv, o[nt], 0, 0, 0);
    }
  }

  // ---- store (C layout: row=quad*4+r, col=lane&15) ----
#pragma unroll
  for (int nt = 0; nt < 4; ++nt) {
#pragma unroll
    for (int r = 0; r < 4; ++r) {
      int grow = row0 + qc * 64 + wave * 16 + quad * 4 + r;
      int gcol = h * 64 + nt * 16 + col;
      out[(size_t)grow * 1024 + gcol] = f2bf(o[nt][r]);
    }
  }
}

// ---------------------------------------------------------------------------
extern "C" void kernel_launch(void* const* d_in, const int* in_sizes, int n_in,
                              void* d_out, int out_size, void* d_ws, size_t ws_size,
                              hipStream_t stream) {
  const float* x        = (const float*)d_in[0];
  const float* time_emb = (const float*)d_in[1];
  const float* norm1_w  = (const float*)d_in[2];
  const float* norm2_w  = (const float*)d_in[3];
  const float* qkv_w    = (const float*)d_in[4];
  const float* out_w    = (const float*)d_in[5];
  const float* w1       = (const float*)d_in[6];
  const float* w2       = (const float*)d_in[7];
  const float* w3       = (const float*)d_in[8];
  const float* mod_w    = (const float*)d_in[9];
  const float* mod_b    = (const float*)d_in[10];
  float* out = (float*)d_out;   // fp32 output per reference dtype

  char* ws = (char*)d_ws;
  float*    mod    = (float*)(ws);                    //  98304 B
  uint16_t* wqkv_t = (uint16_t*)(ws + 98304);         //  (3072,1024) bf16
  uint16_t* wout_t = (uint16_t*)(ws + 6389760);       //  (1024,1024)
  uint16_t* w1t    = (uint16_t*)(ws + 8486912);       //  (2752,1024)
  uint16_t* w2t    = (uint16_t*)(ws + 14123008);      //  (2752,1024)
  uint16_t* w3t    = (uint16_t*)(ws + 19759104);      //  (1024,2752)
  uint16_t* hbuf   = (uint16_t*)(ws + 25395200);      //  (16384,1024) bf16
  uint16_t* qkvb   = (uint16_t*)(ws + 58949632);      //  (16384,3072) bf16
  uint16_t* hid    = qkvb;                            //  (16384,2752) overlay

  dim3 blk(256);
  // weight transposes (fp32 -> bf16, B^T layout)
  transpose_cast<<<dim3(3072 / 32, 1024 / 32), blk, 0, stream>>>(qkv_w, wqkv_t, 1024, 3072);
  transpose_cast<<<dim3(1024 / 32, 1024 / 32), blk, 0, stream>>>(out_w, wout_t, 1024, 1024);
  transpose_cast<<<dim3(2752 / 32, 1024 / 32), blk, 0, stream>>>(w1, w1t, 1024, 2752);
  transpose_cast<<<dim3(2752 / 32, 1024 / 32), blk, 0, stream>>>(w2, w2t, 1024, 2752);
  transpose_cast<<<dim3(1024 / 32, 2752 / 32), blk, 0, stream>>>(w3, w3t, 2752, 1024);

  mod_kernel<<<24, 1024, 0, stream>>>(time_emb, mod_w, mod_b, mod);

  // h = rmsnorm(x)*(1+scale1)+shift1
  norm_kernel<<<16384, blk, 0, stream>>>(x, norm1_w, mod, 0, 1024, hbuf);

  // qkv = h @ qkv_w   (M=16384,N=3072,K=1024)
  gemm_bt<0><<<128 * 24, blk, 0, stream>>>(hbuf, wqkv_t, 16384, 3072, 1024,
                                           qkvb, nullptr, nullptr, nullptr, nullptr);
  // fused attention -> hbuf (reused as attn output)
  attn_kernel<<<4096, blk, 0, stream>>>(qkvb, hbuf);

  // x1 = x + gate1 * (attn @ out_w) -> d_out (fp32)
  gemm_bt<1><<<128 * 8, blk, 0, stream>>>(hbuf, wout_t, 16384, 1024, 1024,
                                          nullptr, x, mod, nullptr, out);
  // h2 = rmsnorm(x1)*(1+scale2)+shift2   (reads fp32 x1 from d_out)
  norm_kernel<<<16384, blk, 0, stream>>>(out, norm2_w, mod, 3072, 4096, hbuf);

  // h1 = silu(h2 @ w1)  (N=2752)
  gemm_bt<2><<<128 * 22, blk, 0, stream>>>(hbuf, w1t, 16384, 2752, 1024,
                                           hid, nullptr, nullptr, nullptr, nullptr);
  // hid = h1 * (h2 @ w2)   (in place over h1)
  gemm_bt<3><<<128 * 22, blk, 0, stream>>>(hbuf, w2t, 16384, 2752, 1024,
                                           hid, nullptr, nullptr, hid, nullptr);
  // out = x1 + gate2 * (hid @ w3)   (fp32 RMW on d_out)
  gemm_bt<4><<<128 * 8, blk, 0, stream>>>(hid, w3t, 16384, 1024, 2752,
                                          nullptr, nullptr, mod, nullptr, out);
}

// Round 3
// 995.289 us; speedup vs baseline: 1.0710x; 1.0710x over previous
//
#include <hip/hip_runtime.h>
#include <stdint.h>

// ---------------------------------------------------------------------------
// TransformerBlock: bf16 MFMA implementation. OUTPUT IS FP32 (reference dtype).
// Round 3: GEMM staging via __builtin_amdgcn_global_load_lds width=16
// (m97 pattern): linear (unpadded) 128x32 LDS tiles, XOR source-swizzle so
// fragment ds_read_b128 is bank-balanced. Everything else unchanged from the
// passing round-2 kernel.
// ---------------------------------------------------------------------------

using bf16x8 = __attribute__((ext_vector_type(8))) short;
using f32x4  = __attribute__((ext_vector_type(4))) float;

typedef __attribute__((address_space(3))) uint16_t lds16_t;

__device__ __forceinline__ float bf2f(uint16_t h) {
  union { uint32_t u; float f; } v; v.u = ((uint32_t)h) << 16; return v.f;
}
__device__ __forceinline__ uint16_t f2bf(float f) {
  union { float f; uint32_t u; } v; v.f = f;
  uint32_t r = v.u + 0x7FFFu + ((v.u >> 16) & 1u);
  return (uint16_t)(r >> 16);
}
__device__ __forceinline__ float silu(float x) { return x / (1.0f + __expf(-x)); }

__device__ __forceinline__ void gload16(const uint16_t* g, lds16_t* l) {
  __builtin_amdgcn_global_load_lds(
      (const __attribute__((address_space(1))) void*)g,
      (__attribute__((address_space(3))) void*)l, 16, 0, 0);
}

// ---------------------------------------------------------------------------
// Transpose-cast: wt[n][k] = (bf16) w[k][n].  w is (K,N) fp32 row-major.
// ---------------------------------------------------------------------------
__global__ __launch_bounds__(256)
void transpose_cast(const float* __restrict__ w, uint16_t* __restrict__ wt,
                    int K, int N) {
  __shared__ float tile[32][33];
  int n0 = blockIdx.x * 32, k0 = blockIdx.y * 32;
  int tx = threadIdx.x & 31, ty = threadIdx.x >> 5;  // ty in [0,8)
#pragma unroll
  for (int it = 0; it < 4; ++it) {
    int r = ty + it * 8;
    tile[r][tx] = w[(k0 + r) * N + n0 + tx];
  }
  __syncthreads();
#pragma unroll
  for (int it = 0; it < 4; ++it) {
    int r = ty + it * 8;
    wt[(n0 + r) * K + k0 + tx] = f2bf(tile[tx][r]);
  }
}

// ---------------------------------------------------------------------------
// mod = silu(time_emb) @ mod_w + mod_b      (4 x 6144, K=1024)
// ---------------------------------------------------------------------------
__global__ __launch_bounds__(1024)
void mod_kernel(const float* __restrict__ te, const float* __restrict__ mw,
                const float* __restrict__ mb, float* __restrict__ mod) {
  __shared__ float ste[4096];          // silu(te) [b][k]
  __shared__ float red[4][4][256];     // [slice][b][col]
  int tid = threadIdx.x;
  for (int i = tid; i < 4096; i += 1024) { float v = te[i]; ste[i] = silu(v); }
  __syncthreads();
  int kslice = tid >> 8, cl = tid & 255;
  int col = blockIdx.x * 256 + cl;
  float acc[4] = {0.f, 0.f, 0.f, 0.f};
  for (int kk = 0; kk < 256; ++kk) {
    int k = kslice * 256 + kk;
    float wv = mw[k * 6144 + col];
#pragma unroll
    for (int b = 0; b < 4; ++b) acc[b] += ste[b * 1024 + k] * wv;
  }
#pragma unroll
  for (int b = 0; b < 4; ++b) red[kslice][b][cl] = acc[b];
  __syncthreads();
  if (kslice == 0) {
#pragma unroll
    for (int b = 0; b < 4; ++b)
      mod[b * 6144 + col] =
          red[0][b][cl] + red[1][b][cl] + red[2][b][cl] + red[3][b][cl] + mb[col];
  }
}

// ---------------------------------------------------------------------------
// RMSNorm + modulation -> bf16.  One block per row (1024 cols, 256 thr x4).
// ---------------------------------------------------------------------------
__global__ __launch_bounds__(256)
void norm_kernel(const float* __restrict__ xf,
                 const float* __restrict__ w, const float* __restrict__ mod,
                 int shift_off, int scale_off, uint16_t* __restrict__ out) {
  int row = blockIdx.x;
  int b = row >> 12;                 // 4096 rows per batch
  int tid = threadIdx.x;
  float4 t = *(const float4*)(xf + (size_t)row * 1024 + tid * 4);
  float v[4] = {t.x, t.y, t.z, t.w};
  float ss = v[0] * v[0] + v[1] * v[1] + v[2] * v[2] + v[3] * v[3];
#pragma unroll
  for (int off = 1; off < 64; off <<= 1) ss += __shfl_xor(ss, off);
  __shared__ float red[4];
  if ((tid & 63) == 0) red[tid >> 6] = ss;
  __syncthreads();
  float tot = red[0] + red[1] + red[2] + red[3];
  float rinv = rsqrtf(tot * (1.0f / 1024.0f) + 1e-6f);
  const float* mrow = mod + b * 6144;
  uint16_t o[4];
#pragma unroll
  for (int c = 0; c < 4; ++c) {
    int col = tid * 4 + c;
    float hv = v[c] * rinv * w[col] * (1.0f + mrow[scale_off + col]) + mrow[shift_off + col];
    o[c] = f2bf(hv);
  }
  uint2 pk;
  pk.x = (uint32_t)o[0] | ((uint32_t)o[1] << 16);
  pk.y = (uint32_t)o[2] | ((uint32_t)o[3] << 16);
  *(uint2*)(out + (size_t)row * 1024 + tid * 4) = pk;
}

// ---------------------------------------------------------------------------
// GEMM: C(M,N) = A(M,K)bf16 @ Bt(N,K)bf16, 128x128x32 tile, 4 waves (2x2),
// each wave 64x64 via 4x4 tiles of v_mfma_f32_16x16x32_bf16.
// Staging: global_load_lds width=16. LDS tiles are linear 128x32 (row-major,
// no pad). XOR swizzle: physical 16B-chunk p of row r holds logical chunk
// p ^ (r&3); the staging *source* address applies the same swizzle, so the
// DMA write stays lane-contiguous and fragment reads stay bank-balanced.
// MODE: 0 store bf16 | 1 x+gate1*C -> fp32 | 2 silu bf16 | 3 h1*C bf16
//       4 xio += gate2*C (fp32 RMW)
// ---------------------------------------------------------------------------
template <int MODE>
__global__ __launch_bounds__(256)
void gemm_bt(const uint16_t* __restrict__ A, const uint16_t* __restrict__ Bt,
             int M, int N, int K,
             uint16_t* __restrict__ obf,
             const float* __restrict__ xin, const float* __restrict__ mod,
             const uint16_t* __restrict__ h1, float* __restrict__ xio) {
  __shared__ uint16_t As[128 * 32];
  __shared__ uint16_t Bs[128 * 32];
  const int tiles_n = (N + 127) >> 7;
  const int tm = blockIdx.x / tiles_n, tn = blockIdx.x % tiles_n;
  const int m0 = tm * 128, n0 = tn * 128;
  const int tid = threadIdx.x;
  const int wave = tid >> 6, lane = tid & 63;
  const int wm = (wave & 1) * 64, wn = (wave >> 1) * 64;
  const int col = lane & 15, quad = lane >> 4;

  // ---- staging addresses: lane covers (row = wave*32 + j*16 + lane>>2,
  //      physical chunk = lane&3); source logical chunk = (lane&3)^(row&3).
  const int lrow = lane >> 2, lchk = lane & 3;
  const int schunk = (lchk ^ (lrow & 3)) << 3;   // element offset in row
  const uint16_t* Ag0 = A + (size_t)(m0 + wave * 32 + lrow) * K + schunk;
  const uint16_t* Ag1 = Ag0 + (size_t)16 * K;
  int br0 = n0 + wave * 32 + lrow;      if (br0 >= N) br0 = N - 1;
  int br1 = n0 + wave * 32 + 16 + lrow; if (br1 >= N) br1 = N - 1;
  const uint16_t* Bg0 = Bt + (size_t)br0 * K + schunk;
  const uint16_t* Bg1 = Bt + (size_t)br1 * K + schunk;
  lds16_t* As3 = (lds16_t*)As;
  lds16_t* Bs3 = (lds16_t*)Bs;
  lds16_t* Aw0 = As3 + wave * 1024;      // rows wave*32 .. +15
  lds16_t* Aw1 = Aw0 + 512;              // rows wave*32+16 .. +31
  lds16_t* Bw0 = Bs3 + wave * 1024;
  lds16_t* Bw1 = Bw0 + 512;

  f32x4 acc[4][4];
#pragma unroll
  for (int i = 0; i < 4; ++i)
#pragma unroll
    for (int j = 0; j < 4; ++j) acc[i][j] = (f32x4){0.f, 0.f, 0.f, 0.f};

  const int swz = (quad ^ (col & 3)) << 3;   // fragment-read chunk offset

  for (int k0 = 0; k0 < K; k0 += 32) {
    __syncthreads();                 // previous iteration's ds_reads done
    gload16(Ag0 + k0, Aw0);
    gload16(Ag1 + k0, Aw1);
    gload16(Bg0 + k0, Bw0);
    gload16(Bg1 + k0, Bw1);
    __syncthreads();                 // drains vmcnt(0): staging visible
    bf16x8 af[4], bfr[4];
#pragma unroll
    for (int i = 0; i < 4; ++i)
      af[i] = *(const bf16x8*)(As + (wm + i * 16 + col) * 32 + swz);
#pragma unroll
    for (int j = 0; j < 4; ++j)
      bfr[j] = *(const bf16x8*)(Bs + (wn + j * 16 + col) * 32 + swz);
#pragma unroll
    for (int i = 0; i < 4; ++i)
#pragma unroll
      for (int j = 0; j < 4; ++j)
        acc[i][j] = __builtin_amdgcn_mfma_f32_16x16x32_bf16(af[i], bfr[j], acc[i][j], 0, 0, 0);
  }

  // epilogue
#pragma unroll
  for (int i = 0; i < 4; ++i) {
#pragma unroll
    for (int j = 0; j < 4; ++j) {
#pragma unroll
      for (int r = 0; r < 4; ++r) {
        int row = m0 + wm + i * 16 + quad * 4 + r;
        int cn = n0 + wn + j * 16 + col;
        if (cn >= N) continue;
        float c = acc[i][j][r];
        if (MODE == 0) {
          obf[(size_t)row * N + cn] = f2bf(c);
        } else if (MODE == 1) {
          int b = row >> 12;
          size_t idx = (size_t)row * 1024 + cn;
          float g = mod[b * 6144 + 2048 + cn];
          xio[idx] = xin[idx] + g * c;
        } else if (MODE == 2) {
          obf[(size_t)row * N + cn] = f2bf(silu(c));
        } else if (MODE == 3) {
          size_t idx = (size_t)row * N + cn;
          obf[idx] = f2bf(bf2f(h1[idx]) * c);
        } else {  // MODE 4
          int b = row >> 12;
          size_t idx = (size_t)row * 1024 + cn;
          float g = mod[b * 6144 + 5120 + cn];
          xio[idx] = xio[idx] + g * c;
        }
      }
    }
  }
}

// ---------------------------------------------------------------------------
// Fused attention: one block per (slice, qchunk); slice=(b*16+t)*16+h, S=256.
// ---------------------------------------------------------------------------
__global__ __launch_bounds__(256)
void attn_kernel(const uint16_t* __restrict__ qkv, uint16_t* __restrict__ out) {
  __shared__ uint16_t lds[32768];  // 64 KB: Ks [0,16384), Vt [16384,32768)
  const int tid = threadIdx.x;
  const int bid = blockIdx.x;
  const int slice = bid >> 2, qc = bid & 3;
  const int bt = slice >> 4, h = slice & 15;
  const int row0 = bt * 256;
  const int wave = tid >> 6, lane = tid & 63;
  const int col = lane & 15, quad = lane >> 4;

  // ---- stage K (swizzled: chunk kc stored at kc ^ (kr&7)) ----
  {
    int kr = tid;
    const uint16_t* kp = qkv + (size_t)(row0 + kr) * 3072 + 1024 + h * 64;
    uint16_t* ks = lds + kr * 64;
#pragma unroll
    for (int kc = 0; kc < 8; ++kc) {
      uint4 v = *(const uint4*)(kp + kc * 8);
      *(uint4*)(ks + ((kc ^ (kr & 7)) << 3)) = v;
    }
  }
  // ---- stage V^T (Vt[d][kr], kr-pair-chunk krc stored at krc ^ (d&7)) ----
  {
    int p = tid & 127, dh = tid >> 7;
    const uint16_t* vp0 = qkv + (size_t)(row0 + 2 * p) * 3072 + 2048 + h * 64 + dh * 32;
    const uint16_t* vp1 = vp0 + 3072;
    uint16_t r0[32], r1[32];
#pragma unroll
    for (int i = 0; i < 4; ++i) {
      *(uint4*)(r0 + i * 8) = *(const uint4*)(vp0 + i * 8);
      *(uint4*)(r1 + i * 8) = *(const uint4*)(vp1 + i * 8);
    }
    uint32_t* vt = (uint32_t*)(lds + 16384);
    int krc = p >> 2;
#pragma unroll
    for (int i = 0; i < 32; ++i) {
      int d = dh * 32 + i;
      uint32_t val = (uint32_t)r0[i] | ((uint32_t)r1[i] << 16);
      vt[d * 128 + ((krc ^ (d & 7)) << 2) + (p & 3)] = val;
    }
  }
  __syncthreads();

  // ---- Q fragments (direct from global) ----
  const int qrow = qc * 64 + wave * 16 + col;
  const uint16_t* qp = qkv + (size_t)(row0 + qrow) * 3072 + h * 64;
  bf16x8 aq0 = *(const bf16x8*)(qp + quad * 8);
  bf16x8 aq1 = *(const bf16x8*)(qp + 32 + quad * 8);

  // ---- scores: S[q][k] = q . k, 16 k-tiles ----
  f32x4 sc[16];
#pragma unroll
  for (int t = 0; t < 16; ++t) {
    int n = t * 16 + col;
    const uint16_t* kb = lds + n * 64;
    bf16x8 b0 = *(const bf16x8*)(kb + ((quad ^ (n & 7)) << 3));
    bf16x8 b1 = *(const bf16x8*)(kb + (((4 + quad) ^ (n & 7)) << 3));
    f32x4 s = (f32x4){0.f, 0.f, 0.f, 0.f};
    s = __builtin_amdgcn_mfma_f32_16x16x32_bf16(aq0, b0, s, 0, 0, 0);
    s = __builtin_amdgcn_mfma_f32_16x16x32_bf16(aq1, b1, s, 0, 0, 0);
    sc[t] = s;
  }

  // ---- softmax over k ----
  const float scale = 0.125f;  // HD^-0.5
  float inv[4];
#pragma unroll
  for (int i = 0; i < 4; ++i) {
    float m = -1e30f;
#pragma unroll
    for (int t = 0; t < 16; ++t) m = fmaxf(m, sc[t][i]);
    m = fmaxf(m, __shfl_xor(m, 1));
    m = fmaxf(m, __shfl_xor(m, 2));
    m = fmaxf(m, __shfl_xor(m, 4));
    m = fmaxf(m, __shfl_xor(m, 8));
    m *= scale;
    float sum = 0.f;
#pragma unroll
    for (int t = 0; t < 16; ++t) {
      float p = __expf(sc[t][i] * scale - m);
      sc[t][i] = p;
      sum += p;
    }
    sum += __shfl_xor(sum, 1);
    sum += __shfl_xor(sum, 2);
    sum += __shfl_xor(sum, 4);
    sum += __shfl_xor(sum, 8);
    inv[i] = 1.0f / sum;
  }
  __syncthreads();  // all waves done reading Ks before P overlays it

  // ---- write P (bf16, A-layout source) into per-wave slice of Ks region ----
  uint16_t* P = lds + wave * 4096;
#pragma unroll
  for (int t = 0; t < 16; ++t) {
    int pcb = t * 2 + (col >> 3);
#pragma unroll
    for (int i = 0; i < 4; ++i) {
      int r = quad * 4 + i;
      P[r * 256 + ((pcb ^ (r & 7)) << 3) + (col & 7)] = f2bf(sc[t][i] * inv[i]);
    }
  }

  // ---- PV ----
  f32x4 o[4];
#pragma unroll
  for (int nt = 0; nt < 4; ++nt) o[nt] = (f32x4){0.f, 0.f, 0.f, 0.f};
  const uint16_t* Vt = lds + 16384;
#pragma unroll
  for (int c = 0; c < 8; ++c) {
    int pc = c * 4 + quad;
    bf16x8 ap = *(const bf16x8*)(P + col * 256 + ((pc ^ (col & 7)) << 3));
#pragma unroll
    for (int nt = 0; nt < 4; ++nt) {
      int d = nt * 16 + col;
      bf16x8 bv = *(const bf16x8*)(Vt + d * 256 + ((pc ^ (d & 7)) << 3));
      o[nt] = __builtin_amdgcn_mfma_f32_16x16x32_bf16(ap, bv, o[nt], 0, 0, 0);
    }
  }

  // ---- store (C layout: row=quad*4+r, col=lane&15) ----
#pragma unroll
  for (int nt = 0; nt < 4; ++nt) {
#pragma unroll
    for (int r = 0; r < 4; ++r) {
      int grow = row0 + qc * 64 + wave * 16 + quad * 4 + r;
      int gcol = h * 64 + nt * 16 + col;
      out[(size_t)grow * 1024 + gcol] = f2bf(o[nt][r]);
    }
  }
}

// ---------------------------------------------------------------------------
extern "C" void kernel_launch(void* const* d_in, const int* in_sizes, int n_in,
                              void* d_out, int out_size, void* d_ws, size_t ws_size,
                              hipStream_t stream) {
  const float* x        = (const float*)d_in[0];
  const float* time_emb = (const float*)d_in[1];
  const float* norm1_w  = (const float*)d_in[2];
  const float* norm2_w  = (const float*)d_in[3];
  const float* qkv_w    = (const float*)d_in[4];
  const float* out_w    = (const float*)d_in[5];
  const float* w1       = (const float*)d_in[6];
  const float* w2       = (const float*)d_in[7];
  const float* w3       = (const float*)d_in[8];
  const float* mod_w    = (const float*)d_in[9];
  const float* mod_b    = (const float*)d_in[10];
  float* out = (float*)d_out;   // fp32 output per reference dtype

  char* ws = (char*)d_ws;
  float*    mod    = (float*)(ws);                    //  98304 B
  uint16_t* wqkv_t = (uint16_t*)(ws + 98304);         //  (3072,1024) bf16
  uint16_t* wout_t = (uint16_t*)(ws + 6389760);       //  (1024,1024)
  uint16_t* w1t    = (uint16_t*)(ws + 8486912);       //  (2752,1024)
  uint16_t* w2t    = (uint16_t*)(ws + 14123008);      //  (2752,1024)
  uint16_t* w3t    = (uint16_t*)(ws + 19759104);      //  (1024,2752)
  uint16_t* hbuf   = (uint16_t*)(ws + 25395200);      //  (16384,1024) bf16
  uint16_t* qkvb   = (uint16_t*)(ws + 58949632);      //  (16384,3072) bf16
  uint16_t* hid    = qkvb;                            //  (16384,2752) overlay

  dim3 blk(256);
  // weight transposes (fp32 -> bf16, B^T layout)
  transpose_cast<<<dim3(3072 / 32, 1024 / 32), blk, 0, stream>>>(qkv_w, wqkv_t, 1024, 3072);
  transpose_cast<<<dim3(1024 / 32, 1024 / 32), blk, 0, stream>>>(out_w, wout_t, 1024, 1024);
  transpose_cast<<<dim3(2752 / 32, 1024 / 32), blk, 0, stream>>>(w1, w1t, 1024, 2752);
  transpose_cast<<<dim3(2752 / 32, 1024 / 32), blk, 0, stream>>>(w2, w2t, 1024, 2752);
  transpose_cast<<<dim3(1024 / 32, 2752 / 32), blk, 0, stream>>>(w3, w3t, 2752, 1024);

  mod_kernel<<<24, 1024, 0, stream>>>(time_emb, mod_w, mod_b, mod);

  // h = rmsnorm(x)*(1+scale1)+shift1
  norm_kernel<<<16384, blk, 0, stream>>>(x, norm1_w, mod, 0, 1024, hbuf);

  // qkv = h @ qkv_w   (M=16384,N=3072,K=1024)
  gemm_bt<0><<<128 * 24, blk, 0, stream>>>(hbuf, wqkv_t, 16384, 3072, 1024,
                                           qkvb, nullptr, nullptr, nullptr, nullptr);
  // fused attention -> hbuf (reused as attn output)
  attn_kernel<<<4096, blk, 0, stream>>>(qkvb, hbuf);

  // x1 = x + gate1 * (attn @ out_w) -> d_out (fp32)
  gemm_bt<1><<<128 * 8, blk, 0, stream>>>(hbuf, wout_t, 16384, 1024, 1024,
                                          nullptr, x, mod, nullptr, out);
  // h2 = rmsnorm(x1)*(1+scale2)+shift2   (reads fp32 x1 from d_out)
  norm_kernel<<<16384, blk, 0, stream>>>(out, norm2_w, mod, 3072, 4096, hbuf);

  // h1 = silu(h2 @ w1)  (N=2752)
  gemm_bt<2><<<128 * 22, blk, 0, stream>>>(hbuf, w1t, 16384, 2752, 1024,
                                           hid, nullptr, nullptr, nullptr, nullptr);
  // hid = h1 * (h2 @ w2)   (in place over h1)
  gemm_bt<3><<<128 * 22, blk, 0, stream>>>(hbuf, w2t, 16384, 2752, 1024,
                                           hid, nullptr, nullptr, hid, nullptr);
  // out = x1 + gate2 * (hid @ w3)   (fp32 RMW on d_out)
  gemm_bt<4><<<128 * 8, blk, 0, stream>>>(hid, w3t, 16384, 1024, 2752,
                                          nullptr, nullptr, mod, nullptr, out);
}